// Round 7
// baseline (290.274 us; speedup 1.0000x reference)
//
#include <hip/hip_runtime.h>

#define BLOCK 512
#define RPB   64           // rows per block: 64 rows x 8 lanes (octet) per row
#define WPH   132          // Wp half-tile LDS row stride (floats): 132%32=4 -> octet lanes distinct banks
#define WS    36           // 32x32 weight LDS row stride: 36%32=4

typedef float v2f __attribute__((ext_vector_type(2)));

// packed FMA: 2 f32 FMAs per instruction (v_pk_fma_f32)
#define PK(ACC_, A_, B_) ACC_ = __builtin_elementwise_fma(A_, B_, ACC_)

// one 4-K chunk of Phase A: 4 e-rows x 3 streams, 24 pk-fma + 4 ds_read_b128
#define CHUNK4(WR_, X0_, X1_, X2_) do {                                         \
    _Pragma("unroll")                                                           \
    for (int e = 0; e < 4; ++e) {                                               \
        const float4 w = *(const float4*)((WR_) + e * (8 * WPH));               \
        const v2f wlo = {w.x, w.y}, whi = {w.z, w.w};                           \
        { const v2f xl = {(X0_).x, (X0_).y}, xh = {(X0_).z, (X0_).w};           \
          PK(pa0[e], xl, wlo); PK(pa0[e], xh, whi); }                           \
        { const v2f xl = {(X1_).x, (X1_).y}, xh = {(X1_).z, (X1_).w};           \
          PK(pa1[e], xl, wlo); PK(pa1[e], xh, whi); }                           \
        { const v2f xl = {(X2_).x, (X2_).y}, xh = {(X2_).z, (X2_).w};           \
          PK(pa2[e], xl, wlo); PK(pa2[e], xh, whi); }                           \
    }                                                                           \
} while (0)

// Octet matvec, ROTATION phases: out[d]=sum_j W[d][j]*in[j]; lane o owns d=o+8e and
// holds in[jj]=x[o+8jj]. Phase p uses col-group g=(o+p)&7 (x broadcast from lane g).
// W stored col-permuted (col j at (j&7)*4+(j>>3)): group g = one float4 at offset 4g.
// Banks: 4*(o + (o+p)%8) mod 32 -> exactly 2-way for all p = conflict-FREE (vs XOR's 8-way).
__device__ __forceinline__ void matvec32(const float* __restrict__ WL, const int o,
                                         const int lbase,  // (tid&63) & ~7: octet base lane
                                         const float* __restrict__ in, float* __restrict__ outv)
{
    v2f o2[4];
    #pragma unroll
    for (int e = 0; e < 4; ++e) o2[e] = (v2f){0.f, 0.f};
    #pragma unroll
    for (int p = 0; p < 8; ++p) {
        const int g = (o + p) & 7;
        float xs[4];
        #pragma unroll
        for (int jj = 0; jj < 4; ++jj)
            xs[jj] = (p == 0) ? in[jj] : __shfl(in[jj], lbase + g);
        const v2f xlo = {xs[0], xs[1]}, xhi = {xs[2], xs[3]};
        const float* wb = WL + o * WS + g * 4;
        #pragma unroll
        for (int e = 0; e < 4; ++e) {
            const float4 w = *(const float4*)(wb + e * (8 * WS));
            const v2f wlo = {w.x, w.y}, whi = {w.z, w.w};
            PK(o2[e], wlo, xlo); PK(o2[e], whi, xhi);
        }
    }
    #pragma unroll
    for (int e = 0; e < 4; ++e) outv[e] = o2[e][0] + o2[e][1];
}

__global__ void __launch_bounds__(BLOCK)
msfe_kernel(
    const float* __restrict__ f1, const float* __restrict__ f4, const float* __restrict__ fD,
    const float* __restrict__ Wp, const float* __restrict__ bp,
    const float* __restrict__ ln_g, const float* __restrict__ ln_b,
    const float* __restrict__ Wq, const float* __restrict__ bq,
    const float* __restrict__ Wk, const float* __restrict__ bk,
    const float* __restrict__ Wv, const float* __restrict__ bv,
    const float* __restrict__ Wo1, const float* __restrict__ bo1,
    const float* __restrict__ Wo2, const float* __restrict__ bo2,
    float* __restrict__ out, int nRows)
{
    __shared__ float Wp_l[32 * WPH];                       // 16.9 KB: one 128-K half of Wp
    __shared__ float A_l[32 * WS];                         // Wq^T Wk / sqrt(D), permuted cols
    __shared__ float Wv_l[32 * WS], Wo1_l[32 * WS], Wo2_l[32 * WS];  // permuted cols
    __shared__ float bp_l[32], g_l[32], b_l[32], u_l[32], v_l[32];
    __shared__ float bv_l[32], bo1_l[32], bo2_l[32];
    __shared__ float c_l;
    // total ~36.4 KB

    const int tid = threadIdx.x;
    const float isq = 0.17677669529663688f;  // 1/sqrt(32)

    // ---- preamble: attention mats + vectors (independent LDS regions) ----
    if (tid < 256) {
        // stage Wv/Wo1/Wo2, octet col-perm: col j -> (j&7)*4 + (j>>3)
        int d = tid >> 3, j4 = tid & 7;
        int base = d * WS + 16 * (j4 & 1) + (j4 >> 1);
        float4 wv = ((const float4*)Wv )[tid];
        float4 w1 = ((const float4*)Wo1)[tid];
        float4 w2 = ((const float4*)Wo2)[tid];
        Wv_l [base] = wv.x; Wv_l [base+4] = wv.y; Wv_l [base+8] = wv.z; Wv_l [base+12] = wv.w;
        Wo1_l[base] = w1.x; Wo1_l[base+4] = w1.y; Wo1_l[base+8] = w1.z; Wo1_l[base+12] = w1.w;
        Wo2_l[base] = w2.x; Wo2_l[base+4] = w2.y; Wo2_l[base+8] = w2.z; Wo2_l[base+12] = w2.w;
        // A = Wq^T Wk * isq (same col-perm), from global (L2-resident)
        float s0 = 0.f, s1 = 0.f, s2 = 0.f, s3 = 0.f;
        #pragma unroll 8
        for (int dd = 0; dd < 32; ++dd) {
            float  wq = Wq[dd * 32 + d];
            float4 wk = *(const float4*)&Wk[dd * 32 + 4 * j4];
            s0 = fmaf(wq, wk.x, s0); s1 = fmaf(wq, wk.y, s1);
            s2 = fmaf(wq, wk.z, s2); s3 = fmaf(wq, wk.w, s3);
        }
        A_l[base] = s0 * isq; A_l[base+4] = s1 * isq; A_l[base+8] = s2 * isq; A_l[base+12] = s3 * isq;
    } else if (tid < 288) {                        // u = (Wk^T bq) * isq
        int a = tid - 256; float s = 0.f;
        #pragma unroll 8
        for (int d = 0; d < 32; ++d) s = fmaf(bq[d], Wk[d * 32 + a], s);
        u_l[a] = s * isq;
    } else if (tid < 320) {                        // v = (Wq^T bk) * isq
        int a = tid - 288; float s = 0.f;
        #pragma unroll 8
        for (int d = 0; d < 32; ++d) s = fmaf(Wq[d * 32 + a], bk[d], s);
        v_l[a] = s * isq;
    } else if (tid == 320) {                       // c = bq.bk * isq
        float s = 0.f;
        #pragma unroll 8
        for (int d = 0; d < 32; ++d) s = fmaf(bq[d], bk[d], s);
        c_l = s * isq;
    } else if (tid >= 480) {
        int a = tid - 480;
        bp_l[a] = bp[a]; g_l[a] = ln_g[a]; b_l[a] = ln_b[a];
    } else if (tid >= 448) {
        int a = tid - 448;
        bv_l[a] = bv[a]; bo1_l[a] = bo1[a]; bo2_l[a] = bo2[a];
    }

    // ---- octet mapping: lane o owns d = o + 8e (e<4); 8 lanes per row ----
    const int o     = tid & 7;
    const int lbase = (tid & 63) & ~7;             // octet base lane within wave
    int row = blockIdx.x * RPB + (tid >> 3);
    const bool active = (row < nRows);
    if (!active) row = nRows - 1;                  // clamp: all lanes reach barriers

    const size_t rowoff = (size_t)row * 256;
    const float* __restrict__ b0 = f1 + rowoff;
    const float* __restrict__ b1 = f4 + rowoff;
    const float* __restrict__ b2 = fD + rowoff;
    const float* wbase = &Wp_l[o * WPH];           // rows o+8e at wbase + e*8*WPH

    v2f pa0[4], pa1[4], pa2[4];
    #pragma unroll
    for (int e = 0; e < 4; ++e) { pa0[e] = (v2f){0.f,0.f}; pa1[e] = (v2f){0.f,0.f}; pa2[e] = (v2f){0.f,0.f}; }

    // ---- stage Wp half 0 (coalesced float4) ----
    #pragma unroll
    for (int i = 0; i < 2; ++i) {
        int idx = tid + i * BLOCK;
        int d = idx >> 5, k4 = idx & 31;
        *(float4*)&Wp_l[d * WPH + 4 * k4] = ((const float4*)Wp)[d * 64 + k4];
    }
    __syncthreads();

    float4 X0 = *(const float4*)(b0),     X1 = *(const float4*)(b1),     X2 = *(const float4*)(b2);
    float4 Y0 = *(const float4*)(b0 + 4), Y1 = *(const float4*)(b1 + 4), Y2 = *(const float4*)(b2 + 4);

    // ---- Phase A half 0: chunk=4 X/Y alternating buffers ----
    #pragma unroll 1
    for (int kc = 0; kc < 128; kc += 8) {
        CHUNK4(wbase + kc, X0, X1, X2);
        if (kc + 8 < 128) {
            X0 = *(const float4*)(b0 + kc + 8);
            X1 = *(const float4*)(b1 + kc + 8);
            X2 = *(const float4*)(b2 + kc + 8);
        }
        CHUNK4(wbase + kc + 4, Y0, Y1, Y2);
        if (kc + 12 < 128) {
            Y0 = *(const float4*)(b0 + kc + 12);
            Y1 = *(const float4*)(b1 + kc + 12);
            Y2 = *(const float4*)(b2 + kc + 12);
        }
    }

    // prefetch half-1 inputs NOW: loads complete during the restage barriers
    X0 = *(const float4*)(b0 + 128); X1 = *(const float4*)(b1 + 128); X2 = *(const float4*)(b2 + 128);
    Y0 = *(const float4*)(b0 + 132); Y1 = *(const float4*)(b1 + 132); Y2 = *(const float4*)(b2 + 132);

    __syncthreads();                               // all waves done reading Wp half 0
    #pragma unroll
    for (int i = 0; i < 2; ++i) {                  // stage Wp half 1
        int idx = tid + i * BLOCK;
        int d = idx >> 5, k4 = idx & 31;
        *(float4*)&Wp_l[d * WPH + 4 * k4] = ((const float4*)Wp)[d * 64 + 32 + k4];
    }
    __syncthreads();

    // ---- Phase A half 1 ----
    #pragma unroll 1
    for (int kc = 0; kc < 128; kc += 8) {
        CHUNK4(wbase + kc, X0, X1, X2);
        if (kc + 8 < 128) {
            X0 = *(const float4*)(b0 + 136 + kc);
            X1 = *(const float4*)(b1 + 136 + kc);
            X2 = *(const float4*)(b2 + 136 + kc);
        }
        CHUNK4(wbase + kc + 4, Y0, Y1, Y2);
        if (kc + 12 < 128) {
            Y0 = *(const float4*)(b0 + 140 + kc);
            Y1 = *(const float4*)(b1 + 140 + kc);
            Y2 = *(const float4*)(b2 + 140 + kc);
        }
    }

    // ---- fold packed accumulators to scalar ----
    float acc0[4], acc1[4], acc2[4];
    #pragma unroll
    for (int e = 0; e < 4; ++e) {
        acc0[e] = pa0[e][0] + pa0[e][1];
        acc1[e] = pa1[e][0] + pa1[e][1];
        acc2[e] = pa2[e][0] + pa2[e][1];
    }

    // ---- bias + ReLU + LayerNorm per stream (octet reduction over 32 dims) ----
    float Xh[3][4];
    float bpe[4], ge[4], be[4];
    #pragma unroll
    for (int e = 0; e < 4; ++e) { bpe[e] = bp_l[o + 8*e]; ge[e] = g_l[o + 8*e]; be[e] = b_l[o + 8*e]; }
    #pragma unroll
    for (int s = 0; s < 3; ++s) {
        float* accp = (s == 0) ? acc0 : (s == 1) ? acc1 : acc2;
        float sm = 0.f, sq = 0.f;
        #pragma unroll
        for (int e = 0; e < 4; ++e) {
            float t = fmaxf(accp[e] + bpe[e], 0.f);
            accp[e] = t; sm += t; sq = fmaf(t, t, sq);
        }
        sm += __shfl_xor(sm, 1); sm += __shfl_xor(sm, 2); sm += __shfl_xor(sm, 4);
        sq += __shfl_xor(sq, 1); sq += __shfl_xor(sq, 2); sq += __shfl_xor(sq, 4);
        float mu  = sm * 0.03125f;
        float var = fmaf(-mu, mu, sq * 0.03125f);
        float inv = rsqrtf(var + 1e-5f);
        #pragma unroll
        for (int e = 0; e < 4; ++e)
            Xh[s][e] = fmaf(ge[e] * (accp[e] - mu), inv, be[e]);
    }

    // ---- scores sc[s][t] = X_s^T A X_t + u.X_t + v.X_s + c ----
    float uX[3], vX[3];
    {
        float uq[4], vq[4];
        #pragma unroll
        for (int e = 0; e < 4; ++e) { uq[e] = u_l[o + 8*e]; vq[e] = v_l[o + 8*e]; }
        #pragma unroll
        for (int t = 0; t < 3; ++t) {
            float us = 0.f, vs = 0.f;
            #pragma unroll
            for (int e = 0; e < 4; ++e) {
                us = fmaf(uq[e], Xh[t][e], us);
                vs = fmaf(vq[e], Xh[t][e], vs);
            }
            us += __shfl_xor(us, 1); us += __shfl_xor(us, 2); us += __shfl_xor(us, 4);
            vs += __shfl_xor(vs, 1); vs += __shfl_xor(vs, 2); vs += __shfl_xor(vs, 4);
            uX[t] = us; vX[t] = vs;
        }
    }

    float sc[9];
    #pragma unroll
    for (int t = 0; t < 3; ++t) {
        float y[4];
        matvec32(A_l, o, lbase, Xh[t], y);         // y[e] = (A X_t)[o+8e], full dot
        #pragma unroll
        for (int s = 0; s < 3; ++s) {
            float p = 0.f;
            #pragma unroll
            for (int e = 0; e < 4; ++e) p = fmaf(Xh[s][e], y[e], p);
            sc[s * 3 + t] = p;                     // partial over my 4 dims
        }
    }
    #pragma unroll
    for (int s = 0; s < 3; ++s)
        #pragma unroll
        for (int t = 0; t < 3; ++t) {
            float p = sc[s * 3 + t];
            p += __shfl_xor(p, 1); p += __shfl_xor(p, 2); p += __shfl_xor(p, 4);
            sc[s * 3 + t] = p + uX[t] + vX[s] + c_l;
        }

    // ---- softmax rows; fold V through xb = sum_t g_t X_t ----
    float g0 = 0.f, g1 = 0.f, g2 = 0.f;
    #pragma unroll
    for (int s = 0; s < 3; ++s) {
        float a0 = sc[s*3+0], a1 = sc[s*3+1], a2 = sc[s*3+2];
        float m  = fmaxf(a0, fmaxf(a1, a2));
        float e0 = __expf(a0 - m), e1 = __expf(a1 - m), e2 = __expf(a2 - m);
        float r  = 1.f / (e0 + e1 + e2);
        g0 = fmaf(e0, r, g0); g1 = fmaf(e1, r, g1); g2 = fmaf(e2, r, g2);
    }
    g0 *= (1.f/3.f); g1 *= (1.f/3.f); g2 *= (1.f/3.f);

    float xb[4];
    #pragma unroll
    for (int e = 0; e < 4; ++e)
        xb[e] = fmaf(g0, Xh[0][e], fmaf(g1, Xh[1][e], g2 * Xh[2][e]));

    // ---- pooled = Wv xb + bv ; h1 = relu(Wo1 pooled + bo1) ; o = Wo2 h1 + bo2 + pooled ----
    float t8[4], ph[4], hh[4];
    matvec32(Wv_l, o, lbase, xb, t8);
    #pragma unroll
    for (int e = 0; e < 4; ++e) ph[e] = t8[e] + bv_l[o + 8 * e];
    matvec32(Wo1_l, o, lbase, ph, t8);
    #pragma unroll
    for (int e = 0; e < 4; ++e) hh[e] = fmaxf(t8[e] + bo1_l[o + 8 * e], 0.f);
    matvec32(Wo2_l, o, lbase, hh, t8);

    float fin[4];
    #pragma unroll
    for (int e = 0; e < 4; ++e) fin[e] = t8[e] + bo2_l[o + 8 * e] + ph[e];

    // ---- intra-octet transpose: lane o gathers F[4o..4o+3] -> one coalesced float4 ----
    const int sb = 4 * (o & 1);
    float ov[4];
    #pragma unroll
    for (int i = 0; i < 4; ++i) {
        float c0 = __shfl(fin[0], sb + i, 8);
        float c1 = __shfl(fin[1], sb + i, 8);
        float c2 = __shfl(fin[2], sb + i, 8);
        float c3 = __shfl(fin[3], sb + i, 8);
        float lo = (o & 2) ? c1 : c0;              // pick e = o>>1
        float hi = (o & 2) ? c3 : c2;
        ov[i] = (o & 4) ? hi : lo;
    }
    if (active)
        *(float4*)(out + (size_t)row * 32 + 4 * o) = make_float4(ov[0], ov[1], ov[2], ov[3]);
}

extern "C" void kernel_launch(void* const* d_in, const int* in_sizes, int n_in,
                              void* d_out, int out_size, void* d_ws, size_t ws_size,
                              hipStream_t stream) {
    const float* f1   = (const float*)d_in[0];
    const float* f4   = (const float*)d_in[1];
    const float* fD   = (const float*)d_in[2];
    const float* Wp   = (const float*)d_in[3];
    const float* bp   = (const float*)d_in[4];
    const float* ln_g = (const float*)d_in[5];
    const float* ln_b = (const float*)d_in[6];
    const float* Wq   = (const float*)d_in[7];
    const float* bq   = (const float*)d_in[8];
    const float* Wk   = (const float*)d_in[9];
    const float* bk   = (const float*)d_in[10];
    const float* Wv   = (const float*)d_in[11];
    const float* bv   = (const float*)d_in[12];
    const float* Wo1  = (const float*)d_in[13];
    const float* bo1  = (const float*)d_in[14];
    const float* Wo2  = (const float*)d_in[15];
    const float* bo2  = (const float*)d_in[16];

    const int nRows  = in_sizes[0] / 256;
    const int blocks = (nRows + RPB - 1) / RPB;

    msfe_kernel<<<blocks, BLOCK, 0, stream>>>(
        f1, f4, fD, Wp, bp, ln_g, ln_b, Wq, bq, Wk, bk, Wv, bv,
        Wo1, bo1, Wo2, bo2, (float*)d_out, nRows);
}